// Round 10
// baseline (257.386 us; speedup 1.0000x reference)
//
#include <hip/hip_runtime.h>
#include <hip/hip_bf16.h>

// TrendEncoder: histogram (B=4096, S=200 -> 256 bins) + 256-step LSTM (H=64).
// Round 10: WAVE-AUTONOMOUS LSTM -- zero barriers in the 256-step loop.
// R4/R6/R7/R8/R9 proved overlap can't be bought while the loop has a
// block-wide barrier (the barrier re-synchronizes any phase offset and the
// convoy eats the gain). So each wave owns 4 batch rows END-TO-END:
//   A-operand = h[m>>2] (4 real rows duplicated across the 16 A-rows), so
//   C/D reg 0 of lane (m,q) is gate row q -- all 4 gates of unit
//   (row q, col 16cg+m) land in-lane with NO cross-wave exchange.
//   16 N-tiles (4 gates x 4 col-groups) x 2 K-chunks = 32 MFMA/wave/step,
//   full W_hh^T resident in VGPRs (128), h in a wave-PRIVATE LDS strip
//   ordered by lgkmcnt only. One __syncthreads total (after histogram).
// C-init trick: only acc.x is ever read (D.x depends only on C.x), so init
// writes just .x (regs .yzw accumulate bounded garbage, never read).
// Act = R5's fused shared-rcp form, gate prescale folded into W/b.

#define B_S     200
#define B_T     256
#define ROWS    16     // rows per block (4 waves x 4 rows)
#define THREADS 256
#define HS      72     // h row stride (fp16 elems); 144 B = 16 B-aligned
#define LOG2E   1.4426950408889634f

typedef __attribute__((ext_vector_type(8))) _Float16 half8;
typedef __attribute__((ext_vector_type(4))) float float4_t;

__device__ __forceinline__ float load_f(const void* p, int i, int isb) {
    if (isb) {
        unsigned short u = ((const unsigned short*)p)[i];
        return __uint_as_float(((unsigned int)u) << 16);
    }
    return ((const float*)p)[i];
}

// fused LSTM cell update (identical numerics to R5): gates prescaled
// (i,f,o by -log2e; g by 2*log2e) upstream in W/b.
__device__ __forceinline__ float act_one(float gi, float gf, float gg,
                                         float go, float& c) {
    float A  = __builtin_amdgcn_exp2f(gi);
    float F  = __builtin_amdgcn_exp2f(gf);
    float Bv = __builtin_amdgcn_exp2f(gg);
    float t1    = (1.0f + A) * (Bv + 1.0f);
    float oneF  = 1.0f + F;
    float numer = fmaf(c, t1, oneF * (Bv - 1.0f));
    float denom = oneF * t1;
    c = numer * __builtin_amdgcn_rcpf(denom);
    float D  = __builtin_amdgcn_exp2f(go);
    float cs = fminf(c * (2.0f * LOG2E), 126.0f);   // inf guard
    float E  = __builtin_amdgcn_exp2f(cs);
    return (E - 1.0f) * __builtin_amdgcn_rcpf((1.0f + D) * (E + 1.0f));
}

__global__ __launch_bounds__(THREADS)
void trend_encoder_kernel(const void* __restrict__ time_,
                          const int*  __restrict__ length,
                          const void* __restrict__ ptime_,
                          const void* __restrict__ wih_,
                          const void* __restrict__ whh_,
                          const void* __restrict__ bih_,
                          const void* __restrict__ bhh_,
                          void* __restrict__ out_) {
    __shared__ __align__(16) float x_t[B_T * ROWS];      // [t][row], 16 KB
    __shared__ __align__(16) _Float16 h_sh[4][4 * HS];   // per-wave private strips
    __shared__ int flag_sh;

    const int tid  = threadIdx.x;
    const int wv   = tid >> 6;        // wave 0..3 -> rows 4wv..4wv+3
    const int lane = tid & 63;
    const int m    = lane & 15;
    const int q    = lane >> 4;
    const int b0   = blockIdx.x * ROWS;

    // ---- dtype probe (wave 0): W_ih ~ U(-0.125,0.125); f32 reinterpreted as
    // bf16 words goes far out of range with overwhelming probability.
    if (tid < 64) {
        unsigned short u = ((const unsigned short*)wih_)[tid];
        float v = __uint_as_float(((unsigned int)u) << 16);
        int bad = !(v > -0.2f && v < 0.2f);
        unsigned long long bm = __ballot(bad);
        if (lane == 0) flag_sh = (bm == 0ULL) ? 1 : 0;
    }
    for (int i = tid; i < B_T * ROWS; i += THREADS) x_t[i] = 0.0f;
    for (int i = tid; i < 4 * 4 * HS; i += THREADS)
        ((_Float16*)h_sh)[i] = (_Float16)0.0f;
    __syncthreads();
    const int isb = flag_sh;

    // ---- histogram: pos = trunc((pt - t)*0.25), add at bin 255-pos (transposed)
    for (int e = tid; e < ROWS * B_S; e += THREADS) {
        int row  = e / B_S;
        int s    = e - row * B_S;
        int grow = b0 + row;
        if (s < length[grow]) {
            float pt = load_f(ptime_, grow, isb);
            float tv = load_f(time_, grow * B_S + s, isb);
            int pos = (int)((pt - tv) * 0.25f);
            if (pos >= 0 && pos < B_T)
                atomicAdd(&x_t[(B_T - 1 - pos) * ROWS + row], 1.0f);
        }
    }

    // ---- resident weights (fp16, gate-prescaled): the FULL W_hh^T.
    // tile (g, cg): gate-col n = 64g + 16cg + m.
    // B-frag: n = lane&15, k = 32c + 8q + j.
    const float gsc[4] = {-LOG2E, -LOG2E, 2.0f * LOG2E, -LOG2E};
    half8 bw[4][4][2];            // 128 VGPRs
    float wihv[4][4], biasv[4][4];
    #pragma unroll
    for (int g = 0; g < 4; ++g) {
        float s = gsc[g];
        #pragma unroll
        for (int cg = 0; cg < 4; ++cg) {
            int n = 64 * g + 16 * cg + m;
            wihv[g][cg]  = load_f(wih_, n, isb) * s;
            biasv[g][cg] = (load_f(bih_, n, isb) + load_f(bhh_, n, isb)) * s;
            #pragma unroll
            for (int c = 0; c < 2; ++c) {
                half8 v;
                #pragma unroll
                for (int j = 0; j < 8; ++j)
                    v[j] = (_Float16)(load_f(whh_, n * 64 + 32 * c + 8 * q + j, isb) * s);
                bw[g][cg][c] = v;
            }
        }
    }

    const int arow = m >> 2;                 // A-operand h row (duplicated x4)
    const int aoff = arow * HS + 8 * q;      // A-frag base (halfs)
    _Float16* hw = h_sh[wv];                 // this wave's private h strip

    float c4[4] = {0.f, 0.f, 0.f, 0.f};     // unit (row q, col 16cg+m)
    float h4[4] = {0.f, 0.f, 0.f, 0.f};
    float4_t acc[4][4];                      // [g][cg]; only .x is ever read
    #pragma unroll
    for (int g = 0; g < 4; ++g)
        #pragma unroll
        for (int cg = 0; cg < 4; ++cg)
            acc[g][cg] = (float4_t){0.f, 0.f, 0.f, 0.f};

    __syncthreads();   // histogram + h init visible; LAST barrier in kernel

    for (int t = 0; t < B_T; ++t) {
        // x for this lane's C row (real row q):
        float xq = x_t[t * ROWS + 4 * wv + q];
        // A fragments: rows m>>2 of this wave's h (lgkmcnt orders vs writes)
        half8 a0 = *(const half8*)&hw[aoff];
        half8 a1 = *(const half8*)&hw[aoff + 32];

        #pragma unroll
        for (int cg = 0; cg < 4; ++cg) {
            #pragma unroll
            for (int g = 0; g < 4; ++g) {
                acc[g][cg][0] = fmaf(xq, wihv[g][cg], biasv[g][cg]);
                acc[g][cg] = __builtin_amdgcn_mfma_f32_16x16x32_f16(
                                 a0, bw[g][cg][0], acc[g][cg], 0, 0, 0);
                acc[g][cg] = __builtin_amdgcn_mfma_f32_16x16x32_f16(
                                 a1, bw[g][cg][1], acc[g][cg], 0, 0, 0);
            }
            // in-lane activation of unit (row q, col 16cg+m)
            h4[cg] = act_one(acc[0][cg][0], acc[1][cg][0],
                             acc[2][cg][0], acc[3][cg][0], c4[cg]);
            hw[q * HS + 16 * cg + m] = (_Float16)h4[cg];
        }
        // no barrier: h strip is wave-private; next iteration's ds_read
        // waits on lgkmcnt for these writes automatically.
    }

    // ---- epilogue: 4 owned outputs (row q, cols 16cg+m)
    #pragma unroll
    for (int cg = 0; cg < 4; ++cg) {
        int o = (b0 + 4 * wv + q) * 64 + 16 * cg + m;
        if (isb) ((__hip_bfloat16*)out_)[o] = __float2bfloat16(h4[cg]);
        else     ((float*)out_)[o] = h4[cg];
    }
}

extern "C" void kernel_launch(void* const* d_in, const int* in_sizes, int n_in,
                              void* d_out, int out_size, void* d_ws, size_t ws_size,
                              hipStream_t stream) {
    const void* time_  = d_in[0];
    const int*  length = (const int*)d_in[1];
    const void* ptime  = d_in[2];
    const void* wih    = d_in[3];
    const void* whh    = d_in[4];
    const void* bih    = d_in[5];
    const void* bhh    = d_in[6];

    const int B = in_sizes[1];   // 4096
    trend_encoder_kernel<<<dim3(B / ROWS), dim3(THREADS), 0, stream>>>(
        time_, length, ptime, wih, whh, bih, bhh, d_out);
}